// Round 4
// baseline (14297.586 us; speedup 1.0000x reference)
//
#include <hip/hip_runtime.h>
#include <hip/hip_bf16.h>

typedef __attribute__((ext_vector_type(8))) short bf16x8;
typedef __attribute__((ext_vector_type(4))) float f32x4;
typedef __attribute__((ext_vector_type(4))) unsigned int u32x4;
typedef unsigned int u32;
typedef unsigned long long u64;

__device__ __forceinline__ short f2bf(float f) {
  __hip_bfloat16 h = __float2bfloat16(f);
  return *reinterpret_cast<short*>(&h);
}
__device__ __forceinline__ float bf2f(short s) {
  __hip_bfloat16 h;
  *reinterpret_cast<short*>(&h) = s;
  return __bfloat162float(h);
}
__device__ __forceinline__ float sigm(float x) { return 1.f / (1.f + __expf(-x)); }

// ---- cache-bypass (MALL-coherent) bulk ops: pipelined, manually waited ----
__device__ __forceinline__ u32x4 ld128(const void* p) {
  u32x4 r;
  asm volatile("global_load_dwordx4 %0, %1, off sc0 sc1"
               : "=v"(r) : "v"((u64)(uintptr_t)p) : "memory");
  return r;
}
__device__ __forceinline__ void st128(void* p, u32x4 v) {
  asm volatile("global_store_dwordx4 %0, %1, off sc0 sc1"
               :: "v"((u64)(uintptr_t)p), "v"(v) : "memory");
}
__device__ __forceinline__ void wait_vm0() {
  asm volatile("s_waitcnt vmcnt(0)" ::: "memory");
  __builtin_amdgcn_sched_barrier(0);
}
__device__ __forceinline__ u32 ld_flag(const u32* p) {
  return __hip_atomic_load(const_cast<u32*>(p), __ATOMIC_RELAXED, __HIP_MEMORY_SCOPE_AGENT);
}
__device__ __forceinline__ void st_prog(u32* p, u32 v) {
  __hip_atomic_store(p, v, __ATOMIC_RELAXED, __HIP_MEMORY_SCOPE_AGENT);
}

__device__ __forceinline__ u32 pk2(float lo, float hi) {
  return ((u32)(unsigned short)f2bf(hi) << 16) | (u32)(unsigned short)f2bf(lo);
}
// decode 8 tagged f32 -> 8 bf16 (16B); ok iff all tags match (|v - tag| < 2)
__device__ __forceinline__ bool dec8(u32x4 a, u32x4 b, float t1f, u32x4& o) {
  float d0 = __uint_as_float(a[0]) - t1f, d1 = __uint_as_float(a[1]) - t1f;
  float d2 = __uint_as_float(a[2]) - t1f, d3 = __uint_as_float(a[3]) - t1f;
  float d4 = __uint_as_float(b[0]) - t1f, d5 = __uint_as_float(b[1]) - t1f;
  float d6 = __uint_as_float(b[2]) - t1f, d7 = __uint_as_float(b[3]) - t1f;
  float m = fmaxf(fmaxf(fmaxf(fabsf(d0), fabsf(d1)), fmaxf(fabsf(d2), fabsf(d3))),
                  fmaxf(fmaxf(fabsf(d4), fabsf(d5)), fmaxf(fabsf(d6), fabsf(d7))));
  o[0] = pk2(d0, d1); o[1] = pk2(d2, d3); o[2] = pk2(d4, d5); o[3] = pk2(d6, d7);
  return m < 2.0f;
}

// ---------------- precompute kernels ----------------
__global__ void swz_generic(const float* __restrict__ src, short* __restrict__ dst,
                            int row_stride, int col_off, int nks, int nunits) {
  int uid = blockIdx.x * blockDim.x + threadIdx.x;
  if (uid >= nunits) return;
  int lane = uid & 63;
  int rem  = uid >> 6;
  int ks = rem % nks;
  int nf = rem / nks;
  int row = nf * 16 + (lane & 15);
  int k0  = col_off + ks * 32 + (lane >> 4) * 8;
  const float* s = src + (size_t)row * row_stride + k0;
  short v[8];
#pragma unroll
  for (int e = 0; e < 8; ++e) v[e] = f2bf(s[e]);
  *reinterpret_cast<int4*>(dst + (size_t)uid * 8) = *reinterpret_cast<int4*>(v);
}

__global__ void xpose_kernel(const int* __restrict__ x, int* __restrict__ xT) {
  int i = blockIdx.x * blockDim.x + threadIdx.x;   // 131072
  int b = i >> 10, t = i & 1023;
  xT[t * 128 + b] = x[i];
}

__global__ __launch_bounds__(512) void table_kernel(
    const float* __restrict__ emb, const short* __restrict__ Wx,
    const float* __restrict__ b0, float* __restrict__ table) {
  __shared__ __align__(16) char smem[65536];
  const int tid = threadIdx.x;
  const int m0 = blockIdx.x * 64;
  const int nt = blockIdx.y;
  for (int i = tid; i < 4096; i += 512) {
    int row = i >> 6, seg = i & 63;
    const float* sp = emb + (size_t)(m0 + row) * 512 + seg * 8;
    short v[8];
#pragma unroll
    for (int e = 0; e < 8; ++e) v[e] = f2bf(sp[e]);
    *reinterpret_cast<int4*>(smem + row * 1024 + ((seg * 16) ^ ((row & 7) << 4))) =
        *reinterpret_cast<int4*>(v);
  }
  __syncthreads();
  const int w = tid >> 6, lane = tid & 63, l15 = lane & 15, lq = lane >> 4;
  const int mg = (w >> 2) * 32, np = w & 3;
  const char* ap = smem + (mg + l15) * 1024;
  const int swz = (l15 & 7) << 4;
  const int nfbase = nt * 8 + np * 2;
  const short* bp0 = Wx + (size_t)nfbase * 8192 + lane * 8;
  const short* bp1 = bp0 + 8192;
  f32x4 acc[2][2] = {};
#pragma unroll 4
  for (int ks = 0; ks < 16; ++ks) {
    int kb = ks * 64 + lq * 16;
    bf16x8 a0 = *reinterpret_cast<const bf16x8*>(ap + (kb ^ swz));
    bf16x8 a1 = *reinterpret_cast<const bf16x8*>(ap + 16 * 1024 + (kb ^ swz));
    bf16x8 bv0 = *reinterpret_cast<const bf16x8*>(bp0 + ks * 512);
    bf16x8 bv1 = *reinterpret_cast<const bf16x8*>(bp1 + ks * 512);
    acc[0][0] = __builtin_amdgcn_mfma_f32_16x16x32_bf16(a0, bv0, acc[0][0], 0, 0, 0);
    acc[1][0] = __builtin_amdgcn_mfma_f32_16x16x32_bf16(a1, bv0, acc[1][0], 0, 0, 0);
    acc[0][1] = __builtin_amdgcn_mfma_f32_16x16x32_bf16(a0, bv1, acc[0][1], 0, 0, 0);
    acc[1][1] = __builtin_amdgcn_mfma_f32_16x16x32_bf16(a1, bv1, acc[1][1], 0, 0, 0);
  }
#pragma unroll
  for (int mf = 0; mf < 2; ++mf)
#pragma unroll
    for (int nfi = 0; nfi < 2; ++nfi)
#pragma unroll
      for (int r = 0; r < 4; ++r) {
        int ncol = nt * 128 + np * 32 + nfi * 16 + l15;
        int vrow = m0 + mg + mf * 16 + lq * 4 + r;
        table[(size_t)vrow * 2048 + ncol] = acc[mf][nfi][r] + b0[ncol];
      }
}

// ---------------- LSTM layer role ----------------
template<int L>
__device__ void lstm_role(char* smem, int rid, int tid,
    const short* __restrict__ Wsw, const float* __restrict__ table,
    const float* __restrict__ bias1, const int* __restrict__ xT,
    float* __restrict__ h0ring, float* __restrict__ h1ring, u32* __restrict__ prog)
{
  const int mh = rid & 1, cg = rid >> 1;
  const int m0 = mh * 64, cbase = cg * 32;
  const int w = tid >> 6, lane = tid & 63;
  const int g = w & 3, mg = (w >> 2) * 32;
  const int l15 = lane & 15, lq = lane >> 4;
  const int swz = (l15 & 7) << 4;
  const int ROWB = (L == 0) ? 1024 : 2048;
  const int NKS  = (L == 0) ? 16 : 32;
  const int nfbase = g * 32 + cg * 2;
  const short* bbase = Wsw + (size_t)nfbase * (NKS * 512) + lane * 8;
  int* xidsl = reinterpret_cast<int*>(smem + 131072);
  const int row_e = tid >> 3, colq = (tid & 7) * 4;
  const int esw = (row_e & 7) << 2;
  float creg[4] = {0.f, 0.f, 0.f, 0.f};
  float4 breg[4];
  if (L == 1) {
#pragma unroll
    for (int gg = 0; gg < 4; ++gg)
      breg[gg] = *reinterpret_cast<const float4*>(bias1 + gg * 512 + cbase + colq);
  }
  const int myprog = ((L == 0) ? 0 : 32) + mh * 16 + cg;
  float* myring = (L == 0) ? h0ring : h1ring;

  for (int t = 0; t < 1024; ++t) {
    // ---- backpressure check, every 4th tick, off critical path normally ----
    if ((t & 3) == 0 && t >= 4) {
      if (tid < 64) {
        u32 tgtA = (u32)(t - 3), tgtB = (u32)(t - 4);
        for (;;) {
          u32 v = 0xffffffffu, tg = 0;
          if (L == 0) {
            if (lane < 16)      { v = ld_flag(&prog[mh * 16 + lane]);            tg = tgtA; }
            else if (lane < 32) { v = ld_flag(&prog[32 + mh * 16 + (lane - 16)]); tg = tgtB; }
          } else {
            if (lane < 16)      { v = ld_flag(&prog[32 + mh * 16 + lane]);       tg = tgtA; }
            else if (lane < 18) { v = ld_flag(&prog[64 + mh * 2 + (lane - 16)]); tg = tgtB; }
          }
          if (__all(v >= tg)) break;
          __builtin_amdgcn_s_sleep(2);
        }
      }
      __syncthreads();
    }
    if (L == 0 && tid < 64) xidsl[tid] = xT[t * 128 + m0 + tid];
    // ---- staging: tagged-f32 retry loads -> bf16 XOR-swizzled LDS ----
    if (L == 0) {
      const float t1f = 4.0f * (float)t;   // tag of h0(t-1)
      const int seg = tid & 63, r0 = tid >> 6;
      const float* sb = h0ring + (size_t)((t + 7) & 7) * 65536 + (size_t)m0 * 512 + seg * 8;
      u32x4 va[8], vb[8];
#pragma unroll
      for (int k = 0; k < 8; ++k) {
        const float* sp = sb + (size_t)(r0 + k * 8) * 512;
        va[k] = ld128(sp); vb[k] = ld128(sp + 4);
      }
      u32 pend = 0xffu;
      for (;;) {
        wait_vm0();
        u32 np = 0;
#pragma unroll
        for (int k = 0; k < 8; ++k) if (pend & (1u << k)) {
          u32x4 o;
          if (dec8(va[k], vb[k], t1f, o)) {
            int r = r0 + k * 8;
            *reinterpret_cast<u32x4*>(smem + r * 1024 + ((seg * 16) ^ ((r & 7) << 4))) = o;
          } else np |= 1u << k;
        }
        if (!np) break;
        pend = np;
#pragma unroll
        for (int k = 0; k < 8; ++k) if (pend & (1u << k)) {
          const float* sp = sb + (size_t)(r0 + k * 8) * 512;
          va[k] = ld128(sp); vb[k] = ld128(sp + 4);
        }
      }
    } else {
      const int segt = tid & 127, r0 = tid >> 7;
      const bool isH0 = segt < 64;
      const float t1f = isH0 ? 4.0f * (float)(t + 1) : 4.0f * (float)t;
      const float* sb = isH0
          ? h0ring + (size_t)(t & 7) * 65536 + (size_t)m0 * 512 + segt * 8
          : h1ring + (size_t)((t + 7) & 7) * 65536 + (size_t)m0 * 512 + (segt - 64) * 8;
      u32x4 va[16], vb[16];
#pragma unroll
      for (int k = 0; k < 16; ++k) {
        const float* sp = sb + (size_t)(r0 + k * 4) * 512;
        va[k] = ld128(sp); vb[k] = ld128(sp + 4);
      }
      u32 pend = 0xffffu;
      for (;;) {
        wait_vm0();
        u32 np = 0;
#pragma unroll
        for (int k = 0; k < 16; ++k) if (pend & (1u << k)) {
          u32x4 o;
          if (dec8(va[k], vb[k], t1f, o)) {
            int r = r0 + k * 4;
            *reinterpret_cast<u32x4*>(smem + r * 2048 + ((segt * 16) ^ ((r & 7) << 4))) = o;
          } else np |= 1u << k;
        }
        if (!np) break;
        pend = np;
#pragma unroll
        for (int k = 0; k < 16; ++k) if (pend & (1u << k)) {
          const float* sp = sb + (size_t)(r0 + k * 4) * 512;
          va[k] = ld128(sp); vb[k] = ld128(sp + 4);
        }
      }
    }
    __syncthreads();
    if (tid == 0) st_prog(&prog[myprog], (u32)(t + 1));
    // ---- table prefetch into regs (L0), overlaps MFMA ----
    float4 tbi, tbf, tbo, tbg;
    if (L == 0) {
      const float* tb = table + (size_t)xidsl[row_e] * 2048 + cbase + colq;
      tbi = *reinterpret_cast<const float4*>(tb);
      tbf = *reinterpret_cast<const float4*>(tb + 512);
      tbo = *reinterpret_cast<const float4*>(tb + 1024);
      tbg = *reinterpret_cast<const float4*>(tb + 1536);
    }
    // ---- MFMA: [64 rows] x [128 gate-cols] ----
    f32x4 acc[2][2] = {};
    const char* ap = smem + (size_t)(mg + l15) * ROWB;
#pragma unroll 4
    for (int ks = 0; ks < NKS; ++ks) {
      int kb = ks * 64 + lq * 16;
      bf16x8 a0 = *reinterpret_cast<const bf16x8*>(ap + (kb ^ swz));
      bf16x8 a1 = *reinterpret_cast<const bf16x8*>(ap + 16 * ROWB + (kb ^ swz));
      bf16x8 b0 = *reinterpret_cast<const bf16x8*>(bbase + ks * 512);
      bf16x8 b1 = *reinterpret_cast<const bf16x8*>(bbase + NKS * 512 + ks * 512);
      acc[0][0] = __builtin_amdgcn_mfma_f32_16x16x32_bf16(a0, b0, acc[0][0], 0, 0, 0);
      acc[1][0] = __builtin_amdgcn_mfma_f32_16x16x32_bf16(a1, b0, acc[1][0], 0, 0, 0);
      acc[0][1] = __builtin_amdgcn_mfma_f32_16x16x32_bf16(a0, b1, acc[0][1], 0, 0, 0);
      acc[1][1] = __builtin_amdgcn_mfma_f32_16x16x32_bf16(a1, b1, acc[1][1], 0, 0, 0);
    }
    __syncthreads();
    // ---- gate exchange via LDS [4][64][32] f32, XOR-swizzled ----
    float* gl = reinterpret_cast<float*>(smem);
#pragma unroll
    for (int mf = 0; mf < 2; ++mf)
#pragma unroll
      for (int nfi = 0; nfi < 2; ++nfi)
#pragma unroll
        for (int r = 0; r < 4; ++r) {
          int lrow = mg + mf * 16 + lq * 4 + r;
          int lcol = (nfi * 16 + l15) ^ ((lrow & 7) << 2);
          gl[(g * 64 + lrow) * 32 + lcol] = acc[mf][nfi][r];
        }
    __syncthreads();
    // ---- elementwise: c in regs, tagged-f32 16B store (no drain, no flag) ----
    float4 Ai = *reinterpret_cast<const float4*>(&gl[(0 * 64 + row_e) * 32 + (colq ^ esw)]);
    float4 Af = *reinterpret_cast<const float4*>(&gl[(1 * 64 + row_e) * 32 + (colq ^ esw)]);
    float4 Ao = *reinterpret_cast<const float4*>(&gl[(2 * 64 + row_e) * 32 + (colq ^ esw)]);
    float4 Ag = *reinterpret_cast<const float4*>(&gl[(3 * 64 + row_e) * 32 + (colq ^ esw)]);
    float4 bi, bf_, bo, bg;
    if (L == 0) { bi = tbi; bf_ = tbf; bo = tbo; bg = tbg; }
    else { bi = breg[0]; bf_ = breg[1]; bo = breg[2]; bg = breg[3]; }
    float gi_[4] = {Ai.x + bi.x, Ai.y + bi.y, Ai.z + bi.z, Ai.w + bi.w};
    float gf_[4] = {Af.x + bf_.x, Af.y + bf_.y, Af.z + bf_.z, Af.w + bf_.w};
    float go_[4] = {Ao.x + bo.x, Ao.y + bo.y, Ao.z + bo.z, Ao.w + bo.w};
    float gg_[4] = {Ag.x + bg.x, Ag.y + bg.y, Ag.z + bg.z, Ag.w + bg.w};
    const float t1o = 4.0f * (float)(t + 1);
    u32x4 ov;
#pragma unroll
    for (int j = 0; j < 4; ++j) {
      float cv = sigm(gf_[j]) * creg[j] + sigm(gi_[j]) * tanhf(gg_[j]);
      creg[j] = cv;
      ov[j] = __float_as_uint(t1o + sigm(go_[j]) * tanhf(cv));
    }
    st128(myring + (size_t)(t & 7) * 65536 + (size_t)(m0 + row_e) * 512 + cbase + colq, ov);
    __syncthreads();   // gl reads done -> next tick may overwrite staging LDS
  }
}

// ---------------- projection role (LN + [32x256] K=512 GEMM) ----------------
__device__ void proj_role(char* smem, int pid, int tid,
    const float* __restrict__ h1ring, u32* __restrict__ prog,
    const short* __restrict__ pWswz, const float* __restrict__ lng,
    const float* __restrict__ lnb, const float* __restrict__ pb,
    float* __restrict__ out)
{
  const int prow0 = pid * 32;
  const int w = tid >> 6, lane = tid & 63, l15 = lane & 15, lq = lane >> 4;
  const int swz = (l15 & 7) << 4;
  const short* bp0 = pWswz + (size_t)(w * 2) * 8192 + lane * 8;
  const short* bp1 = bp0 + 8192;

  for (int t = 0; t < 1024; ++t) {
    // ---- stage h1(t) rows with tag-retry -> bf16 LDS [32][512] ----
    {
      const float t1f = 4.0f * (float)(t + 1);
      const int seg = tid & 63, r0 = tid >> 6;
      const float* sb = h1ring + (size_t)(t & 7) * 65536 + (size_t)prow0 * 512 + seg * 8;
      u32x4 va[4], vb[4];
#pragma unroll
      for (int k = 0; k < 4; ++k) {
        const float* sp = sb + (size_t)(r0 + k * 8) * 512;
        va[k] = ld128(sp); vb[k] = ld128(sp + 4);
      }
      u32 pend = 0xfu;
      for (;;) {
        wait_vm0();
        u32 np = 0;
#pragma unroll
        for (int k = 0; k < 4; ++k) if (pend & (1u << k)) {
          u32x4 o;
          if (dec8(va[k], vb[k], t1f, o)) {
            int r = r0 + k * 8;
            *reinterpret_cast<u32x4*>(smem + r * 1024 + seg * 16) = o;
          } else np |= 1u << k;
        }
        if (!np) break;
        pend = np;
#pragma unroll
        for (int k = 0; k < 4; ++k) if (pend & (1u << k)) {
          const float* sp = sb + (size_t)(r0 + k * 8) * 512;
          va[k] = ld128(sp); vb[k] = ld128(sp + 4);
        }
      }
    }
    __syncthreads();
    if (tid == 0) st_prog(&prog[64 + pid], (u32)(t + 1));
    {
      int row = tid >> 4, j = tid & 15;
      const short* hr = reinterpret_cast<const short*>(smem) + row * 512;
      float s1 = 0.f, s2 = 0.f;
#pragma unroll
      for (int kk = 0; kk < 32; ++kk) {
        float v = bf2f(hr[kk * 16 + j]);
        s1 += v; s2 += v * v;
      }
#pragma unroll
      for (int d = 1; d < 16; d <<= 1) { s1 += __shfl_xor(s1, d, 64); s2 += __shfl_xor(s2, d, 64); }
      float mu = s1 * (1.f / 512.f);
      float rs = rsqrtf(s2 * (1.f / 512.f) - mu * mu + 1e-5f);
      char* zn = smem + 32768;
#pragma unroll
      for (int kk = 0; kk < 32; ++kk) {
        int k = kk * 16 + j;
        float v = bf2f(hr[k]);
        float nv = (v - mu) * rs * lng[k] + lnb[k];
        *reinterpret_cast<short*>(zn + row * 1024 + ((k * 2) ^ ((row & 7) << 4))) = f2bf(nv);
      }
    }
    __syncthreads();
    const char* ap = smem + 32768 + l15 * 1024;
    f32x4 acc[2][2] = {};
#pragma unroll 4
    for (int ks = 0; ks < 16; ++ks) {
      int kb = ks * 64 + lq * 16;
      bf16x8 a0 = *reinterpret_cast<const bf16x8*>(ap + (kb ^ swz));
      bf16x8 a1 = *reinterpret_cast<const bf16x8*>(ap + 16 * 1024 + (kb ^ swz));
      bf16x8 bv0 = *reinterpret_cast<const bf16x8*>(bp0 + ks * 512);
      bf16x8 bv1 = *reinterpret_cast<const bf16x8*>(bp1 + ks * 512);
      acc[0][0] = __builtin_amdgcn_mfma_f32_16x16x32_bf16(a0, bv0, acc[0][0], 0, 0, 0);
      acc[1][0] = __builtin_amdgcn_mfma_f32_16x16x32_bf16(a1, bv0, acc[1][0], 0, 0, 0);
      acc[0][1] = __builtin_amdgcn_mfma_f32_16x16x32_bf16(a0, bv1, acc[0][1], 0, 0, 0);
      acc[1][1] = __builtin_amdgcn_mfma_f32_16x16x32_bf16(a1, bv1, acc[1][1], 0, 0, 0);
    }
#pragma unroll
    for (int mf = 0; mf < 2; ++mf)
#pragma unroll
      for (int nfi = 0; nfi < 2; ++nfi)
#pragma unroll
        for (int r = 0; r < 4; ++r) {
          int vcol = (w * 2 + nfi) * 16 + l15;
          int rowg = prow0 + mf * 16 + lq * 4 + r;
          out[(size_t)rowg * 262144 + (size_t)t * 256 + vcol] = acc[mf][nfi][r] + pb[vcol];
        }
    __syncthreads();
  }
}

__global__ __launch_bounds__(512, 2) void persist_kernel(
    const short* __restrict__ W0h, const short* __restrict__ W1,
    const float* __restrict__ table, const float* __restrict__ bias1,
    const int* __restrict__ xT, float* __restrict__ h0ring, float* __restrict__ h1ring,
    u32* __restrict__ prog,
    const short* __restrict__ pWswz, const float* __restrict__ lng,
    const float* __restrict__ lnb, const float* __restrict__ pb, float* __restrict__ out)
{
  __shared__ __align__(16) char smem[131328];
  const int wg = blockIdx.x, tid = threadIdx.x;
  if (wg < 32)
    lstm_role<0>(smem, wg, tid, W0h, table, nullptr, xT, h0ring, h1ring, prog);
  else if (wg < 64)
    lstm_role<1>(smem, wg - 32, tid, W1, nullptr, bias1, xT, h0ring, h1ring, prog);
  else
    proj_role(smem, wg - 64, tid, h1ring, prog, pWswz, lng, lnb, pb, out);
}

extern "C" void kernel_launch(void* const* d_in, const int* in_sizes, int n_in,
                              void* d_out, int out_size, void* d_ws, size_t ws_size,
                              hipStream_t stream) {
  const int*   x    = (const int*)d_in[0];
  const float* emb  = (const float*)d_in[1];
  const float* W    = (const float*)d_in[2];
  const float* bias = (const float*)d_in[3];
  const float* lng  = (const float*)d_in[4];
  const float* lnb  = (const float*)d_in[5];
  const float* pW   = (const float*)d_in[6];
  const float* pb   = (const float*)d_in[7];
  float* out = (float*)d_out;

  char* ws = (char*)d_ws;
  short* W0h   = (short*)(ws + 0);           // 2 MB
  short* W1sw  = (short*)(ws + 2097152);     // 4 MB
  short* pWsw  = (short*)(ws + 6291456);     // 256 KB
  float* table = (float*)(ws + 6553600);     // 2 MB
  int*   xT    = (int*)(ws + 8650752);       // 512 KB
  u32*   prog  = (u32*)(ws + 9175040);       // 272 B (padded to 9437184)
  float* h0ring= (float*)(ws + 9437184);     // 2 MB: 8 x [128][512] f32 tagged
  float* h1ring= (float*)(ws + 11534336);    // 2 MB
  short* W0x   = (short*)(ws + 9437184);     // temp alias over h0ring (table build)

  swz_generic<<<dim3(512), dim3(256), 0, stream>>>(W, W0h, 1024, 512, 16, 131072);
  swz_generic<<<dim3(1024), dim3(256), 0, stream>>>(W + 2048 * 1024, W1sw, 1024, 0, 32, 262144);
  swz_generic<<<dim3(64), dim3(256), 0, stream>>>(pW, pWsw, 512, 0, 16, 16384);
  xpose_kernel<<<dim3(512), dim3(256), 0, stream>>>(x, xT);
  swz_generic<<<dim3(512), dim3(256), 0, stream>>>(W, W0x, 1024, 0, 16, 131072);
  table_kernel<<<dim3(4, 16), dim3(512), 0, stream>>>(emb, W0x, bias, table);
  // after table build: init prog + zero slot 7 of both rings (t=0 reads, tag 0)
  hipMemsetAsync(ws + 9175040, 0, 272, stream);
  hipMemsetAsync(ws + 9437184 + 7 * 262144, 0, 262144, stream);
  hipMemsetAsync(ws + 11534336 + 7 * 262144, 0, 262144, stream);

  persist_kernel<<<dim3(68), dim3(512), 0, stream>>>(
      W0h, W1sw, table, bias + 2048, xT, h0ring, h1ring, prog,
      pWsw, lng, lnb, pb, out);
}

// Round 6
// 5776.940 us; speedup vs baseline: 2.4749x; 2.4749x over previous
//
#include <hip/hip_runtime.h>
#include <hip/hip_bf16.h>

typedef __attribute__((ext_vector_type(8))) short bf16x8;
typedef __attribute__((ext_vector_type(4))) float f32x4;
typedef __attribute__((ext_vector_type(4))) unsigned int u32x4;
typedef unsigned int u32;
typedef unsigned long long u64;
typedef unsigned short u16;

__device__ __forceinline__ short f2bf(float f) {
  __hip_bfloat16 h = __float2bfloat16(f);
  return *reinterpret_cast<short*>(&h);
}
__device__ __forceinline__ float bf2f(u16 s) {
  __hip_bfloat16 h;
  *reinterpret_cast<u16*>(&h) = s;
  return __bfloat162float(h);
}
__device__ __forceinline__ float sigm(float x) { return 1.f / (1.f + __expf(-x)); }

// ---- MALL-coherent transport (R3/R4-proven semantics) ----
__device__ __forceinline__ u32x4 ld128_sys(const void* p) {
  u32x4 r;
  asm volatile("global_load_dwordx4 %0, %1, off sc0 sc1"
               : "=v"(r) : "v"((u64)(uintptr_t)p) : "memory");
  return r;
}
__device__ __forceinline__ void st32_sys(void* p, u32 v) {
  asm volatile("global_store_dword %0, %1, off sc0 sc1"
               :: "v"((u64)(uintptr_t)p), "v"(v) : "memory");
}
__device__ __forceinline__ void vm_drain() {
  asm volatile("s_waitcnt vmcnt(0)" ::: "memory");
  __builtin_amdgcn_sched_barrier(0);
}
__device__ __forceinline__ u32 ld_flag(const u32* p) {
  return __hip_atomic_load(const_cast<u32*>(p), __ATOMIC_RELAXED, __HIP_MEMORY_SCOPE_AGENT);
}
__device__ __forceinline__ void st_flag(u32* p, u32 v) {
  __hip_atomic_store(p, v, __ATOMIC_RELAXED, __HIP_MEMORY_SCOPE_AGENT);
}

// ---------------- precompute kernels ----------------
__global__ void swz_generic(const float* __restrict__ src, short* __restrict__ dst,
                            int row_stride, int col_off, int nks, int nunits) {
  int uid = blockIdx.x * blockDim.x + threadIdx.x;
  if (uid >= nunits) return;
  int lane = uid & 63;
  int rem  = uid >> 6;
  int ks = rem % nks;
  int nf = rem / nks;
  int row = nf * 16 + (lane & 15);
  int k0  = col_off + ks * 32 + (lane >> 4) * 8;
  const float* s = src + (size_t)row * row_stride + k0;
  short v[8];
#pragma unroll
  for (int e = 0; e < 8; ++e) v[e] = f2bf(s[e]);
  *reinterpret_cast<int4*>(dst + (size_t)uid * 8) = *reinterpret_cast<int4*>(v);
}

__global__ void xpose_kernel(const int* __restrict__ x, int* __restrict__ xT) {
  int i = blockIdx.x * blockDim.x + threadIdx.x;   // 131072
  int b = i >> 10, t = i & 1023;
  xT[t * 128 + b] = x[i];
}

__global__ __launch_bounds__(512) void table_kernel(
    const float* __restrict__ emb, const short* __restrict__ Wx,
    const float* __restrict__ b0, float* __restrict__ table) {
  __shared__ __align__(16) char smem[65536];
  const int tid = threadIdx.x;
  const int m0 = blockIdx.x * 64;
  const int nt = blockIdx.y;
  for (int i = tid; i < 4096; i += 512) {
    int row = i >> 6, seg = i & 63;
    const float* sp = emb + (size_t)(m0 + row) * 512 + seg * 8;
    short v[8];
#pragma unroll
    for (int e = 0; e < 8; ++e) v[e] = f2bf(sp[e]);
    *reinterpret_cast<int4*>(smem + row * 1024 + ((seg * 16) ^ ((row & 7) << 4))) =
        *reinterpret_cast<int4*>(v);
  }
  __syncthreads();
  const int w = tid >> 6, lane = tid & 63, l15 = lane & 15, lq = lane >> 4;
  const int mg = (w >> 2) * 32, np = w & 3;
  const char* ap = smem + (mg + l15) * 1024;
  const int swz = (l15 & 7) << 4;
  const int nfbase = nt * 8 + np * 2;
  const short* bp0 = Wx + (size_t)nfbase * 8192 + lane * 8;
  const short* bp1 = bp0 + 8192;
  f32x4 acc[2][2] = {};
#pragma unroll 4
  for (int ks = 0; ks < 16; ++ks) {
    int kb = ks * 64 + lq * 16;
    bf16x8 a0 = *reinterpret_cast<const bf16x8*>(ap + (kb ^ swz));
    bf16x8 a1 = *reinterpret_cast<const bf16x8*>(ap + 16 * 1024 + (kb ^ swz));
    bf16x8 bv0 = *reinterpret_cast<const bf16x8*>(bp0 + ks * 512);
    bf16x8 bv1 = *reinterpret_cast<const bf16x8*>(bp1 + ks * 512);
    acc[0][0] = __builtin_amdgcn_mfma_f32_16x16x32_bf16(a0, bv0, acc[0][0], 0, 0, 0);
    acc[1][0] = __builtin_amdgcn_mfma_f32_16x16x32_bf16(a1, bv0, acc[1][0], 0, 0, 0);
    acc[0][1] = __builtin_amdgcn_mfma_f32_16x16x32_bf16(a0, bv1, acc[0][1], 0, 0, 0);
    acc[1][1] = __builtin_amdgcn_mfma_f32_16x16x32_bf16(a1, bv1, acc[1][1], 0, 0, 0);
  }
#pragma unroll
  for (int mf = 0; mf < 2; ++mf)
#pragma unroll
    for (int nfi = 0; nfi < 2; ++nfi)
#pragma unroll
      for (int r = 0; r < 4; ++r) {
        int ncol = nt * 128 + np * 32 + nfi * 16 + l15;
        int vrow = m0 + mg + mf * 16 + lq * 4 + r;
        table[(size_t)vrow * 2048 + ncol] = acc[mf][nfi][r] + b0[ncol];
      }
}

// ---------------- LSTM role (M_wg = 16 rows) ----------------
// L0: 64 WGs (bg 0..7 x cs 0..7): N_wg=256 (64 h-cols), K=512 (h-part; x via table)
// L1: 128 WGs (bg 0..7 x cs 0..15): N_wg=128 (32 h-cols), K=1024
template<int L>
__device__ void lstm_role(char* smem, int bg, int cs, int tid,
    const short* __restrict__ Wsw, const float* __restrict__ table,
    const float* __restrict__ bias1, const int* __restrict__ xT,
    u16* __restrict__ h0ring, u16* __restrict__ h1ring, u32* __restrict__ flags)
{
  constexpr int NCOL = (L == 0) ? 64 : 32;     // h-cols per WG
  constexpr int NKS  = (L == 0) ? 16 : 32;     // K / 32
  constexpr int ROWB = (L == 0) ? 1024 : 2048; // A row bytes
  const int w = tid >> 6, lane = tid & 63, l15 = lane & 15, lq = lane >> 4;
  const int g = w >> 1;                        // gate 0..3
  const int m0 = bg * 16;
  u32* F  = flags;          // ready
  u32* FP = flags + 1024;   // prog
  const int myid = (L == 0) ? (128 + bg * 8 + cs) : (bg * 16 + cs);
  // B pointers
  const int nf0 = g * 32 + cs * (NCOL / 16) + (w & 1) * ((L == 0) ? 2 : 1);
  const short* bb0 = Wsw + (size_t)nf0 * (NKS * 512) + lane * 8;
  const short* bb1 = (L == 0) ? bb0 + (size_t)(NKS * 512) : nullptr;
  float* glf = reinterpret_cast<float*>(smem + ((L == 0) ? 16384 : 32768)); // [4][16][NCOL]
  int* xids = reinterpret_cast<int*>(smem + ((L == 0) ? 32768 : 40960));
  const int swzrow = (l15 & 7) << 4;
  // elementwise ownership
  const bool ew = (L == 0) ? true : (tid < 256);
  const int erow = (L == 0) ? (tid >> 5) : (tid >> 4);
  const int ecp  = (L == 0) ? ((tid & 31) * 2) : ((tid & 15) * 2);
  float c0 = 0.f, c1 = 0.f;
  float2 breg[4];
  if (L == 1 && ew) {
#pragma unroll
    for (int gg = 0; gg < 4; ++gg)
      breg[gg] = *reinterpret_cast<const float2*>(bias1 + gg * 512 + cs * 32 + ecp);
  }

  for (int t = 0; t < 1024; ++t) {
    // ---- poll (wave0, per-lane independent spin) ----
    const bool chk = ((t & 7) == 0) && (t >= 16);
    if (w == 0) {
      const u32* a = nullptr; u32 tgt = 0;
      if (L == 0) {
        if (t > 0) {
          if (lane < 8)       { a = &F[(128 + bg * 8 + lane) * 4]; tgt = (u32)t; }
          else if (lane < 24) { if (chk) { a = &FP[(bg * 16 + lane - 8) * 4]; tgt = (u32)(t - 6); } }
          else if (lane < 32) { if (chk) { a = &FP[(128 + bg * 8 + lane - 24) * 4]; tgt = (u32)(t - 6); } }
        }
      } else {
        if (lane < 8)       { a = &F[(128 + bg * 8 + lane) * 4]; tgt = (u32)(t + 1); }
        else if (lane < 24) { if (t >= 1) { a = &F[(bg * 16 + lane - 8) * 4]; tgt = (u32)t; } }
        else if (lane < 40) { if (chk) { a = &FP[(bg * 16 + lane - 24) * 4]; tgt = (u32)(t - 6); } }
        else if (lane == 40){ if (chk) { a = &FP[(192 + bg) * 4]; tgt = (u32)(t - 6); } }
      }
      if (a) while (ld_flag(a) < tgt) __builtin_amdgcn_s_sleep(1);
    }
    if (L == 0 && tid < 16) xids[tid] = xT[t * 128 + m0 + tid];
    __syncthreads();
    // ---- stage A into LDS (bf16, XOR-swizzled rows) ----
    if (L == 0) {
      const u16* src0 = h0ring + (size_t)((t + 15) & 15) * 65536;
#pragma unroll
      for (int k = 0; k < 2; ++k) {
        int c = tid * 2 + k;
        int r = c >> 6, seg = c & 63;
        u32x4 v = {0, 0, 0, 0};
        if (t > 0) v = ld128_sys(src0 + (size_t)(m0 + r) * 512 + seg * 8);
        vm_drain();
        *reinterpret_cast<u32x4*>(smem + r * 1024 + ((seg * 16) ^ ((r & 7) << 4))) = v;
      }
    } else {
      const u16* s0 = h0ring + (size_t)(t & 15) * 65536;
      const u16* s1 = h1ring + (size_t)((t + 15) & 15) * 65536;
      u32x4 v[4];
#pragma unroll
      for (int k = 0; k < 4; ++k) {
        int c = tid * 4 + k;
        int part = c >> 10, cc = c & 1023;
        int r = cc >> 6, seg = cc & 63;
        if (part == 0)      v[k] = ld128_sys(s0 + (size_t)(m0 + r) * 512 + seg * 8);
        else if (t > 0)     v[k] = ld128_sys(s1 + (size_t)(m0 + r) * 512 + seg * 8);
        else                v[k] = u32x4{0, 0, 0, 0};
      }
      vm_drain();
#pragma unroll
      for (int k = 0; k < 4; ++k) {
        int c = tid * 4 + k;
        int part = c >> 10, cc = c & 1023;
        int r = cc >> 6, seg = cc & 63;
        *reinterpret_cast<u32x4*>(smem + r * 2048 + (((part * 64 + seg) * 16) ^ ((r & 7) << 4))) = v[k];
      }
    }
    __syncthreads();
    if (tid == 0) st_flag(&FP[myid * 4], (u32)(t + 1));
    // ---- table prefetch (L0) ----
    float2 tb[4];
    if (L == 0) {
      const float* tp = table + (size_t)xids[erow] * 2048 + cs * 64 + ecp;
      tb[0] = *reinterpret_cast<const float2*>(tp);
      tb[1] = *reinterpret_cast<const float2*>(tp + 512);
      tb[2] = *reinterpret_cast<const float2*>(tp + 1024);
      tb[3] = *reinterpret_cast<const float2*>(tp + 1536);
    }
    // ---- MFMA ----
    const char* ap = smem + (size_t)l15 * ROWB;
    if (L == 0) {
      f32x4 acc[2][2] = {};
#pragma unroll 4
      for (int ks = 0; ks < NKS; ++ks) {
        bf16x8 a = *reinterpret_cast<const bf16x8*>(ap + ((ks * 64 + lq * 16) ^ swzrow));
        bf16x8 b0 = *reinterpret_cast<const bf16x8*>(bb0 + ks * 512);
        bf16x8 b1 = *reinterpret_cast<const bf16x8*>(bb1 + ks * 512);
        acc[0][ks & 1] = __builtin_amdgcn_mfma_f32_16x16x32_bf16(a, b0, acc[0][ks & 1], 0, 0, 0);
        acc[1][ks & 1] = __builtin_amdgcn_mfma_f32_16x16x32_bf16(a, b1, acc[1][ks & 1], 0, 0, 0);
      }
      __syncthreads();   // A fully consumed
#pragma unroll
      for (int nfi = 0; nfi < 2; ++nfi) {
        f32x4 rr;
        rr[0] = acc[nfi][0][0] + acc[nfi][1][0]; rr[1] = acc[nfi][0][1] + acc[nfi][1][1];
        rr[2] = acc[nfi][0][2] + acc[nfi][1][2]; rr[3] = acc[nfi][0][3] + acc[nfi][1][3];
        int col = ((w & 1) * 2 + nfi) * 16 + l15;
#pragma unroll
        for (int r = 0; r < 4; ++r)
          glf[(g * 16 + lq * 4 + r) * 64 + col] = rr[r];
      }
    } else {
      f32x4 acca = {}, accb = {};
#pragma unroll 4
      for (int ks = 0; ks < NKS; ++ks) {
        bf16x8 a = *reinterpret_cast<const bf16x8*>(ap + ((ks * 64 + lq * 16) ^ swzrow));
        bf16x8 b0 = *reinterpret_cast<const bf16x8*>(bb0 + ks * 512);
        if (ks & 1) accb = __builtin_amdgcn_mfma_f32_16x16x32_bf16(a, b0, accb, 0, 0, 0);
        else        acca = __builtin_amdgcn_mfma_f32_16x16x32_bf16(a, b0, acca, 0, 0, 0);
      }
      __syncthreads();
      {
        int col = (w & 1) * 16 + l15;
#pragma unroll
        for (int r = 0; r < 4; ++r)
          glf[(g * 16 + lq * 4 + r) * 32 + col] = acca[r] + accb[r];
      }
    }
    __syncthreads();
    // ---- elementwise + h store ----
    if (ew) {
      float2 vi = *reinterpret_cast<float2*>(&glf[(0 * 16 + erow) * NCOL + ecp]);
      float2 vf = *reinterpret_cast<float2*>(&glf[(1 * 16 + erow) * NCOL + ecp]);
      float2 vo = *reinterpret_cast<float2*>(&glf[(2 * 16 + erow) * NCOL + ecp]);
      float2 vg = *reinterpret_cast<float2*>(&glf[(3 * 16 + erow) * NCOL + ecp]);
      float bi0, bi1, bf0, bf1, bo0, bo1, bg0, bg1;
      if (L == 0) {
        bi0 = tb[0].x; bi1 = tb[0].y; bf0 = tb[1].x; bf1 = tb[1].y;
        bo0 = tb[2].x; bo1 = tb[2].y; bg0 = tb[3].x; bg1 = tb[3].y;
      } else {
        bi0 = breg[0].x; bi1 = breg[0].y; bf0 = breg[1].x; bf1 = breg[1].y;
        bo0 = breg[2].x; bo1 = breg[2].y; bg0 = breg[3].x; bg1 = breg[3].y;
      }
      float cv0 = sigm(vf.x + bf0) * c0 + sigm(vi.x + bi0) * tanhf(vg.x + bg0);
      float cv1 = sigm(vf.y + bf1) * c1 + sigm(vi.y + bi1) * tanhf(vg.y + bg1);
      c0 = cv0; c1 = cv1;
      float h0v = sigm(vo.x + bo0) * tanhf(cv0);
      float h1v = sigm(vo.y + bo1) * tanhf(cv1);
      u32 pk = (u32)(u16)f2bf(h0v) | ((u32)(u16)f2bf(h1v) << 16);
      u16* ring = (L == 0) ? h0ring : h1ring;
      size_t eo = (size_t)(t & 15) * 65536 + (size_t)(m0 + erow) * 512 + cs * NCOL + ecp;
      st32_sys(ring + eo, pk);
    }
    vm_drain();
    __syncthreads();
    if (tid == 0) st_flag(&F[myid * 4], (u32)(t + 1));
  }
}

// ---------------- projection role (LN + [16x256] K=512 GEMM) ----------------
__device__ void proj_role(char* smem, int bg, int tid,
    const u16* __restrict__ h1ring, u32* __restrict__ flags,
    const short* __restrict__ pWswz, const float* __restrict__ lng,
    const float* __restrict__ lnb, const float* __restrict__ pb,
    float* __restrict__ out)
{
  const int w = tid >> 6, lane = tid & 63, l15 = lane & 15, lq = lane >> 4;
  const int m0 = bg * 16;
  u32* F  = flags;
  u32* FP = flags + 1024;
  const short* bp0 = pWswz + (size_t)(w * 2) * 8192 + lane * 8;
  const short* bp1 = bp0 + 8192;
  const int swzrow = (l15 & 7) << 4;
  float pb0 = pb[(w * 2) * 16 + l15], pb1 = pb[(w * 2 + 1) * 16 + l15];

  for (int t = 0; t < 1024; ++t) {
    if (w == 0 && lane < 16) {
      const u32* a = &F[(bg * 16 + lane) * 4];
      while (ld_flag(a) < (u32)(t + 1)) __builtin_amdgcn_s_sleep(1);
    }
    __syncthreads();
    const u16* src = h1ring + (size_t)(t & 15) * 65536;
#pragma unroll
    for (int k = 0; k < 2; ++k) {
      int c = tid * 2 + k;
      int r = c >> 6, seg = c & 63;
      u32x4 v = ld128_sys(src + (size_t)(m0 + r) * 512 + seg * 8);
      vm_drain();
      *reinterpret_cast<u32x4*>(smem + r * 1024 + seg * 16) = v;
    }
    __syncthreads();
    if (tid == 0) st_flag(&FP[(192 + bg) * 4], (u32)(t + 1));
    // LayerNorm: 32 threads/row, 16 elems each
    {
      int row = tid >> 5, j = tid & 31;
      const u16* hr = reinterpret_cast<const u16*>(smem) + row * 512;
      float s1 = 0.f, s2 = 0.f;
#pragma unroll
      for (int kk = 0; kk < 16; ++kk) {
        float v = bf2f(hr[j + kk * 32]);
        s1 += v; s2 += v * v;
      }
#pragma unroll
      for (int d = 1; d < 32; d <<= 1) { s1 += __shfl_xor(s1, d, 32); s2 += __shfl_xor(s2, d, 32); }
      float mu = s1 * (1.f / 512.f);
      float rs = rsqrtf(s2 * (1.f / 512.f) - mu * mu + 1e-5f);
      char* zn = smem + 16384;
#pragma unroll
      for (int kk = 0; kk < 16; ++kk) {
        int kcol = j + kk * 32;
        float v = bf2f(hr[kcol]);
        float nv = (v - mu) * rs * lng[kcol] + lnb[kcol];
        *reinterpret_cast<short*>(zn + row * 1024 + ((kcol * 2) ^ ((row & 7) << 4))) = f2bf(nv);
      }
    }
    __syncthreads();
    const char* ap = smem + 16384 + (size_t)l15 * 1024;
    f32x4 acc[2][2] = {};
#pragma unroll 4
    for (int ks = 0; ks < 16; ++ks) {
      bf16x8 a = *reinterpret_cast<const bf16x8*>(ap + ((ks * 64 + lq * 16) ^ swzrow));
      bf16x8 b0 = *reinterpret_cast<const bf16x8*>(bp0 + ks * 512);
      bf16x8 b1 = *reinterpret_cast<const bf16x8*>(bp1 + ks * 512);
      acc[0][ks & 1] = __builtin_amdgcn_mfma_f32_16x16x32_bf16(a, b0, acc[0][ks & 1], 0, 0, 0);
      acc[1][ks & 1] = __builtin_amdgcn_mfma_f32_16x16x32_bf16(a, b1, acc[1][ks & 1], 0, 0, 0);
    }
#pragma unroll
    for (int nfi = 0; nfi < 2; ++nfi) {
      int vcol = (w * 2 + nfi) * 16 + l15;
      float pbv = nfi ? pb1 : pb0;
#pragma unroll
      for (int r = 0; r < 4; ++r) {
        float vv = acc[nfi][0][r] + acc[nfi][1][r] + pbv;
        out[(size_t)(m0 + lq * 4 + r) * 262144 + (size_t)t * 256 + vcol] = vv;
      }
    }
    __syncthreads();
  }
}

// Grid: 200 blocks. 0..127 = L1 (bg*16+cs), 128..191 = L0 (bg*8+cs), 192..199 = proj.
__global__ __launch_bounds__(512, 1) void persist_kernel(
    const short* __restrict__ W0h, const short* __restrict__ W1,
    const float* __restrict__ table, const float* __restrict__ bias1,
    const int* __restrict__ xT,
    u16* __restrict__ h0ring, u16* __restrict__ h1ring, u32* __restrict__ flags,
    const short* __restrict__ pWswz, const float* __restrict__ lng,
    const float* __restrict__ lnb, const float* __restrict__ pb, float* __restrict__ out)
{
  __shared__ __align__(16) char smem[49408];
  const int bid = blockIdx.x, tid = threadIdx.x;
  if (bid < 128) {
    lstm_role<1>(smem, bid >> 4, bid & 15, tid, W1, nullptr, bias1, xT,
                 h0ring, h1ring, flags);
  } else if (bid < 192) {
    int idx = bid - 128;
    lstm_role<0>(smem, idx >> 3, idx & 7, tid, W0h, table, nullptr, xT,
                 h0ring, h1ring, flags);
  } else {
    proj_role(smem, bid - 192, tid, h1ring, flags, pWswz, lng, lnb, pb, out);
  }
}

extern "C" void kernel_launch(void* const* d_in, const int* in_sizes, int n_in,
                              void* d_out, int out_size, void* d_ws, size_t ws_size,
                              hipStream_t stream) {
  const int*   x    = (const int*)d_in[0];
  const float* emb  = (const float*)d_in[1];
  const float* W    = (const float*)d_in[2];
  const float* bias = (const float*)d_in[3];
  const float* lng  = (const float*)d_in[4];
  const float* lnb  = (const float*)d_in[5];
  const float* pW   = (const float*)d_in[6];
  const float* pb   = (const float*)d_in[7];
  float* out = (float*)d_out;

  char* ws = (char*)d_ws;
  short* W0h   = (short*)(ws + 0);           // 2 MB  [nf 0..127][ks 0..15]
  short* W1sw  = (short*)(ws + 2097152);     // 4 MB  [nf 0..127][ks 0..31]
  short* pWsw  = (short*)(ws + 6291456);     // 256 KB
  float* table = (float*)(ws + 6815744);     // 2 MB  [256][2048]
  int*   xT    = (int*)(ws + 8912896);       // 512 KB
  u32*   flags = (u32*)(ws + 9437184);       // 8 KB (ready 4K | prog 4K)
  u16*   h0ring= (u16*)(ws + 9961472);       // 2 MB: 16 x [128][512] bf16
  u16*   h1ring= (u16*)(ws + 12058624);      // 2 MB
  short* W0x   = (short*)(ws + 14155776);    // 2 MB temp (table build)

  swz_generic<<<dim3(512), dim3(256), 0, stream>>>(W, W0h, 1024, 512, 16, 131072);
  swz_generic<<<dim3(1024), dim3(256), 0, stream>>>(W + 2048 * 1024, W1sw, 1024, 0, 32, 262144);
  swz_generic<<<dim3(64), dim3(256), 0, stream>>>(pW, pWsw, 512, 0, 16, 16384);
  xpose_kernel<<<dim3(512), dim3(256), 0, stream>>>(x, xT);
  swz_generic<<<dim3(512), dim3(256), 0, stream>>>(W, W0x, 1024, 0, 16, 131072);
  table_kernel<<<dim3(4, 16), dim3(512), 0, stream>>>(emb, W0x, bias, table);
  hipMemsetAsync(ws + 9437184, 0, 8192, stream);   // flags

  persist_kernel<<<dim3(200), dim3(512), 0, stream>>>(
      W0h, W1sw, table, bias + 2048, xT, h0ring, h1ring, flags,
      pWsw, lng, lnb, pb, out);
}

// Round 7
// 5011.520 us; speedup vs baseline: 2.8529x; 1.1527x over previous
//
#include <hip/hip_runtime.h>
#include <hip/hip_bf16.h>

typedef __attribute__((ext_vector_type(8))) short bf16x8;
typedef __attribute__((ext_vector_type(4))) float f32x4;
typedef __attribute__((ext_vector_type(4))) unsigned int u32x4;
typedef unsigned int u32;
typedef unsigned long long u64;
typedef unsigned short u16;

__device__ __forceinline__ short f2bf(float f) {
  __hip_bfloat16 h = __float2bfloat16(f);
  return *reinterpret_cast<short*>(&h);
}
__device__ __forceinline__ float bf2f(u16 s) {
  __hip_bfloat16 h;
  *reinterpret_cast<u16*>(&h) = s;
  return __bfloat162float(h);
}
__device__ __forceinline__ float sigm(float x) { return 1.f / (1.f + __expf(-x)); }

// ---- MALL-coherent transport ----
__device__ __forceinline__ u32x4 ld128_sys(const void* p) {
  u32x4 r;
  asm volatile("global_load_dwordx4 %0, %1, off sc0 sc1"
               : "=v"(r) : "v"((u64)(uintptr_t)p) : "memory");
  return r;
}
__device__ __forceinline__ void st32_sys(void* p, u32 v) {
  asm volatile("global_store_dword %0, %1, off sc0 sc1"
               :: "v"((u64)(uintptr_t)p), "v"(v) : "memory");
}
__device__ __forceinline__ void vm_drain() {
  asm volatile("s_waitcnt vmcnt(0)" ::: "memory");
  __builtin_amdgcn_sched_barrier(0);
}
__device__ __forceinline__ u32 ld_flag(const u32* p) {
  return __hip_atomic_load(const_cast<u32*>(p), __ATOMIC_RELAXED, __HIP_MEMORY_SCOPE_AGENT);
}
__device__ __forceinline__ void st_flag(u32* p, u32 v) {
  __hip_atomic_store(p, v, __ATOMIC_RELAXED, __HIP_MEMORY_SCOPE_AGENT);
}
// parity check: all 8 bf16 LSBs in a 16B granule == p?  (pm = p ? 0x00010001 : 0)
__device__ __forceinline__ bool par_ok(u32x4 v, u32 pm) {
  u32 z = ((v[0] ^ pm) | (v[1] ^ pm) | (v[2] ^ pm) | (v[3] ^ pm)) & 0x00010001u;
  return z == 0;
}

// ---------------- precompute kernels ----------------
__global__ void swz_generic(const float* __restrict__ src, short* __restrict__ dst,
                            int row_stride, int col_off, int nks, int nunits) {
  int uid = blockIdx.x * blockDim.x + threadIdx.x;
  if (uid >= nunits) return;
  int lane = uid & 63;
  int rem  = uid >> 6;
  int ks = rem % nks;
  int nf = rem / nks;
  int row = nf * 16 + (lane & 15);
  int k0  = col_off + ks * 32 + (lane >> 4) * 8;
  const float* s = src + (size_t)row * row_stride + k0;
  short v[8];
#pragma unroll
  for (int e = 0; e < 8; ++e) v[e] = f2bf(s[e]);
  *reinterpret_cast<int4*>(dst + (size_t)uid * 8) = *reinterpret_cast<int4*>(v);
}

__global__ void xpose_kernel(const int* __restrict__ x, int* __restrict__ xT) {
  int i = blockIdx.x * blockDim.x + threadIdx.x;   // 131072
  int b = i >> 10, t = i & 1023;
  xT[t * 128 + b] = x[i];
}

__global__ __launch_bounds__(512) void table_kernel(
    const float* __restrict__ emb, const short* __restrict__ Wx,
    const float* __restrict__ b0, float* __restrict__ table) {
  __shared__ __align__(16) char smem[65536];
  const int tid = threadIdx.x;
  const int m0 = blockIdx.x * 64;
  const int nt = blockIdx.y;
  for (int i = tid; i < 4096; i += 512) {
    int row = i >> 6, seg = i & 63;
    const float* sp = emb + (size_t)(m0 + row) * 512 + seg * 8;
    short v[8];
#pragma unroll
    for (int e = 0; e < 8; ++e) v[e] = f2bf(sp[e]);
    *reinterpret_cast<int4*>(smem + row * 1024 + ((seg * 16) ^ ((row & 7) << 4))) =
        *reinterpret_cast<int4*>(v);
  }
  __syncthreads();
  const int w = tid >> 6, lane = tid & 63, l15 = lane & 15, lq = lane >> 4;
  const int mg = (w >> 2) * 32, np = w & 3;
  const char* ap = smem + (mg + l15) * 1024;
  const int swz = (l15 & 7) << 4;
  const int nfbase = nt * 8 + np * 2;
  const short* bp0 = Wx + (size_t)nfbase * 8192 + lane * 8;
  const short* bp1 = bp0 + 8192;
  f32x4 acc[2][2] = {};
#pragma unroll 4
  for (int ks = 0; ks < 16; ++ks) {
    int kb = ks * 64 + lq * 16;
    bf16x8 a0 = *reinterpret_cast<const bf16x8*>(ap + (kb ^ swz));
    bf16x8 a1 = *reinterpret_cast<const bf16x8*>(ap + 16 * 1024 + (kb ^ swz));
    bf16x8 bv0 = *reinterpret_cast<const bf16x8*>(bp0 + ks * 512);
    bf16x8 bv1 = *reinterpret_cast<const bf16x8*>(bp1 + ks * 512);
    acc[0][0] = __builtin_amdgcn_mfma_f32_16x16x32_bf16(a0, bv0, acc[0][0], 0, 0, 0);
    acc[1][0] = __builtin_amdgcn_mfma_f32_16x16x32_bf16(a1, bv0, acc[1][0], 0, 0, 0);
    acc[0][1] = __builtin_amdgcn_mfma_f32_16x16x32_bf16(a0, bv1, acc[0][1], 0, 0, 0);
    acc[1][1] = __builtin_amdgcn_mfma_f32_16x16x32_bf16(a1, bv1, acc[1][1], 0, 0, 0);
  }
#pragma unroll
  for (int mf = 0; mf < 2; ++mf)
#pragma unroll
    for (int nfi = 0; nfi < 2; ++nfi)
#pragma unroll
      for (int r = 0; r < 4; ++r) {
        int ncol = nt * 128 + np * 32 + nfi * 16 + l15;
        int vrow = m0 + mg + mf * 16 + lq * 4 + r;
        table[(size_t)vrow * 2048 + ncol] = acc[mf][nfi][r] + b0[ncol];
      }
}

// ---------------- LSTM role (M_wg = 16 rows) ----------------
template<int L>
__device__ void lstm_role(char* smem, int bg, int cs, int tid,
    const short* __restrict__ Wsw, const float* __restrict__ table,
    const float* __restrict__ bias1, const int* __restrict__ xT,
    u16* __restrict__ h0ring, u16* __restrict__ h1ring, u32* __restrict__ FP)
{
  constexpr int NCOL = (L == 0) ? 64 : 32;
  constexpr int NKS  = (L == 0) ? 16 : 32;
  constexpr int ROWB = (L == 0) ? 1024 : 2048;
  const int w = tid >> 6, lane = tid & 63, l15 = lane & 15, lq = lane >> 4;
  const int g = w >> 1;
  const int m0 = bg * 16;
  const int myid = (L == 0) ? (128 + bg * 8 + cs) : (bg * 16 + cs);
  const int nf0 = g * 32 + cs * (NCOL / 16) + (w & 1) * ((L == 0) ? 2 : 1);
  const short* bb0 = Wsw + (size_t)nf0 * (NKS * 512) + lane * 8;
  const short* bb1 = (L == 0) ? bb0 + (size_t)(NKS * 512) : nullptr;
  float* glf = reinterpret_cast<float*>(smem + ((L == 0) ? 16384 : 32768));
  int* xids = reinterpret_cast<int*>(smem + ((L == 0) ? 32768 : 40960));
  const int swzrow = (l15 & 7) << 4;
  const bool ew = (L == 0) ? true : (tid < 256);
  const int erow = (L == 0) ? (tid >> 5) : (tid >> 4);
  const int ecp  = (L == 0) ? ((tid & 31) * 2) : ((tid & 15) * 2);
  const int esh  = ((erow >> 2) & 3) * 8;          // gate-exchange rotation
  float c0 = 0.f, c1 = 0.f;
  float2 breg[4];
  if (L == 1 && ew) {
#pragma unroll
    for (int gg = 0; gg < 4; ++gg)
      breg[gg] = *reinterpret_cast<const float2*>(bias1 + gg * 512 + cs * 32 + ecp);
  }

  for (int t = 0; t < 1024; ++t) {
    // ---- backpressure (every 8 ticks, FP only) ----
    if (((t & 7) == 0) && t >= 16) {
      if (w == 0) {
        const u32* a = nullptr;
        if (L == 0) {
          if (lane < 16)      a = &FP[(bg * 16 + lane) * 4];          // L1 consumers of h0
          else if (lane < 24) a = &FP[(128 + bg * 8 + lane - 16) * 4];// L0 peers
        } else {
          if (lane < 16)      a = &FP[(bg * 16 + lane) * 4];          // L1 peers
          else if (lane == 16) a = &FP[(192 + bg) * 4];               // proj
        }
        if (a) { u32 tgt = (u32)(t - 6); while (ld_flag(a) < tgt) __builtin_amdgcn_s_sleep(1); }
      }
    }
    if (L == 0 && tid < 16) xids[tid] = xT[t * 128 + m0 + tid];
    __syncthreads();
    // ---- stage A: parity-validated retry loads -> bf16 XOR-swizzled LDS ----
    if (L == 0) {
      const u32 pm = (((t - 1) >> 4) & 1) ? 0x00010001u : 0u;  // h0 epoch t-1
      const u16* s0 = h0ring + (size_t)((t + 15) & 15) * 65536 + (size_t)m0 * 512;
      u32x4 v[2];
      int pend = 0;
#pragma unroll
      for (int k = 0; k < 2; ++k) {
        int gidx = tid + k * 512;
        int rr = gidx >> 6, seg = gidx & 63;
        if (t > 0) { v[k] = ld128_sys(s0 + rr * 512 + seg * 8); pend |= 1 << k; }
        else {
          v[k] = u32x4{0, 0, 0, 0};
          *reinterpret_cast<u32x4*>(smem + rr * 1024 + ((seg * 16) ^ ((rr & 7) << 4))) = v[k];
        }
      }
      while (pend) {
        vm_drain();
        int np = 0;
#pragma unroll
        for (int k = 0; k < 2; ++k) if (pend & (1 << k)) {
          int gidx = tid + k * 512;
          int rr = gidx >> 6, seg = gidx & 63;
          if (par_ok(v[k], pm))
            *reinterpret_cast<u32x4*>(smem + rr * 1024 + ((seg * 16) ^ ((rr & 7) << 4))) = v[k];
          else { np |= 1 << k; v[k] = ld128_sys(s0 + rr * 512 + seg * 8); }
        }
        pend = np;
      }
    } else {
      const u32 pm0 = ((t >> 4) & 1) ? 0x00010001u : 0u;         // h0 epoch t
      const u32 pm1 = (((t - 1) >> 4) & 1) ? 0x00010001u : 0u;   // h1 epoch t-1
      const u16* s0 = h0ring + (size_t)(t & 15) * 65536 + (size_t)m0 * 512;
      const u16* s1 = h1ring + (size_t)((t + 15) & 15) * 65536 + (size_t)m0 * 512;
      u32x4 v[4];
      int pend = 0;
#pragma unroll
      for (int k = 0; k < 4; ++k) {
        int gidx = tid + k * 512;
        int part = gidx >> 10, rr = (gidx >> 6) & 15, seg = gidx & 63;
        if (part == 0) { v[k] = ld128_sys(s0 + rr * 512 + seg * 8); pend |= 1 << k; }
        else if (t > 0) { v[k] = ld128_sys(s1 + rr * 512 + seg * 8); pend |= 1 << k; }
        else {
          v[k] = u32x4{0, 0, 0, 0};
          *reinterpret_cast<u32x4*>(smem + rr * 2048 + (((64 + seg) * 16) ^ ((rr & 7) << 4))) = v[k];
        }
      }
      while (pend) {
        vm_drain();
        int np = 0;
#pragma unroll
        for (int k = 0; k < 4; ++k) if (pend & (1 << k)) {
          int gidx = tid + k * 512;
          int part = gidx >> 10, rr = (gidx >> 6) & 15, seg = gidx & 63;
          if (par_ok(v[k], part ? pm1 : pm0))
            *reinterpret_cast<u32x4*>(smem + rr * 2048 + (((part * 64 + seg) * 16) ^ ((rr & 7) << 4))) = v[k];
          else {
            np |= 1 << k;
            v[k] = ld128_sys((part ? s1 : s0) + rr * 512 + seg * 8);
          }
        }
        pend = np;
      }
    }
    __syncthreads();
    if (tid == 0) st_flag(&FP[myid * 4], (u32)(t + 1));
    // ---- table prefetch (L0) ----
    float2 tb[4];
    if (L == 0) {
      const float* tp = table + (size_t)xids[erow] * 2048 + cs * 64 + ecp;
      tb[0] = *reinterpret_cast<const float2*>(tp);
      tb[1] = *reinterpret_cast<const float2*>(tp + 512);
      tb[2] = *reinterpret_cast<const float2*>(tp + 1024);
      tb[3] = *reinterpret_cast<const float2*>(tp + 1536);
    }
    // ---- MFMA ----
    const char* ap = smem + (size_t)l15 * ROWB;
    if (L == 0) {
      f32x4 acc[2][2] = {};
#pragma unroll 4
      for (int ks = 0; ks < NKS; ++ks) {
        bf16x8 a = *reinterpret_cast<const bf16x8*>(ap + ((ks * 64 + lq * 16) ^ swzrow));
        bf16x8 b0 = *reinterpret_cast<const bf16x8*>(bb0 + ks * 512);
        bf16x8 b1 = *reinterpret_cast<const bf16x8*>(bb1 + ks * 512);
        acc[0][ks & 1] = __builtin_amdgcn_mfma_f32_16x16x32_bf16(a, b0, acc[0][ks & 1], 0, 0, 0);
        acc[1][ks & 1] = __builtin_amdgcn_mfma_f32_16x16x32_bf16(a, b1, acc[1][ks & 1], 0, 0, 0);
      }
      __syncthreads();
#pragma unroll
      for (int nfi = 0; nfi < 2; ++nfi) {
        int col = ((w & 1) * 2 + nfi) * 16 + l15;
#pragma unroll
        for (int r = 0; r < 4; ++r) {
          int lrow = lq * 4 + r;
          glf[(g * 16 + lrow) * 64 + ((col + (lrow >> 2) * 8) & 63)] =
              acc[nfi][0][r] + acc[nfi][1][r];
        }
      }
    } else {
      f32x4 acca = {}, accb = {};
#pragma unroll 4
      for (int ks = 0; ks < NKS; ++ks) {
        bf16x8 a = *reinterpret_cast<const bf16x8*>(ap + ((ks * 64 + lq * 16) ^ swzrow));
        bf16x8 b0 = *reinterpret_cast<const bf16x8*>(bb0 + ks * 512);
        if (ks & 1) accb = __builtin_amdgcn_mfma_f32_16x16x32_bf16(a, b0, accb, 0, 0, 0);
        else        acca = __builtin_amdgcn_mfma_f32_16x16x32_bf16(a, b0, acca, 0, 0, 0);
      }
      __syncthreads();
      {
        int col = (w & 1) * 16 + l15;
#pragma unroll
        for (int r = 0; r < 4; ++r) {
          int lrow = lq * 4 + r;
          glf[(g * 16 + lrow) * 32 + ((col + (lrow >> 2) * 8) & 31)] = acca[r] + accb[r];
        }
      }
    }
    __syncthreads();
    // ---- elementwise: c in regs, parity-packed 4B store (no drain, no flag) ----
    if (ew) {
      float2 vi = *reinterpret_cast<float2*>(&glf[(0 * 16 + erow) * NCOL + ((ecp + esh) & (NCOL - 1))]);
      float2 vf = *reinterpret_cast<float2*>(&glf[(1 * 16 + erow) * NCOL + ((ecp + esh) & (NCOL - 1))]);
      float2 vo = *reinterpret_cast<float2*>(&glf[(2 * 16 + erow) * NCOL + ((ecp + esh) & (NCOL - 1))]);
      float2 vg = *reinterpret_cast<float2*>(&glf[(3 * 16 + erow) * NCOL + ((ecp + esh) & (NCOL - 1))]);
      float bi0, bi1, bf0, bf1, bo0, bo1, bg0, bg1;
      if (L == 0) {
        bi0 = tb[0].x; bi1 = tb[0].y; bf0 = tb[1].x; bf1 = tb[1].y;
        bo0 = tb[2].x; bo1 = tb[2].y; bg0 = tb[3].x; bg1 = tb[3].y;
      } else {
        bi0 = breg[0].x; bi1 = breg[0].y; bf0 = breg[1].x; bf1 = breg[1].y;
        bo0 = breg[2].x; bo1 = breg[2].y; bg0 = breg[3].x; bg1 = breg[3].y;
      }
      float cv0 = sigm(vf.x + bf0) * c0 + sigm(vi.x + bi0) * tanhf(vg.x + bg0);
      float cv1 = sigm(vf.y + bf1) * c1 + sigm(vi.y + bi1) * tanhf(vg.y + bg1);
      c0 = cv0; c1 = cv1;
      float h0v = sigm(vo.x + bo0) * tanhf(cv0);
      float h1v = sigm(vo.y + bo1) * tanhf(cv1);
      u32 po = (u32)((t >> 4) & 1);
      u32 pk = (((u32)(u16)f2bf(h0v) & ~1u) | po)
             | ((((u32)(u16)f2bf(h1v) & ~1u) | po) << 16);
      u16* ring = (L == 0) ? h0ring : h1ring;
      size_t eo = (size_t)(t & 15) * 65536 + (size_t)(m0 + erow) * 512 + cs * NCOL + ecp;
      st32_sys(ring + eo, pk);
    }
    __syncthreads();
  }
  vm_drain();   // flush final h stores before exit (last consumers still polling)
}

// ---------------- projection role ----------------
__device__ void proj_role(char* smem, int bg, int tid,
    const u16* __restrict__ h1ring, u32* __restrict__ FP,
    const short* __restrict__ pWswz, const float* __restrict__ lng,
    const float* __restrict__ lnb, const float* __restrict__ pb,
    float* __restrict__ out)
{
  const int w = tid >> 6, lane = tid & 63, l15 = lane & 15, lq = lane >> 4;
  const int m0 = bg * 16;
  const short* bp0 = pWswz + (size_t)(w * 2) * 8192 + lane * 8;
  const short* bp1 = bp0 + 8192;
  const int swzrow = (l15 & 7) << 4;
  float pb0 = pb[(w * 2) * 16 + l15], pb1 = pb[(w * 2 + 1) * 16 + l15];

  for (int t = 0; t < 1024; ++t) {
    {
      const u32 pm = ((t >> 4) & 1) ? 0x00010001u : 0u;   // h1 epoch t
      const u16* src = h1ring + (size_t)(t & 15) * 65536 + (size_t)m0 * 512;
      u32x4 v[2];
      int pend = 3;
#pragma unroll
      for (int k = 0; k < 2; ++k) {
        int gidx = tid + k * 512;
        int rr = gidx >> 6, seg = gidx & 63;
        v[k] = ld128_sys(src + rr * 512 + seg * 8);
      }
      while (pend) {
        vm_drain();
        int np = 0;
#pragma unroll
        for (int k = 0; k < 2; ++k) if (pend & (1 << k)) {
          int gidx = tid + k * 512;
          int rr = gidx >> 6, seg = gidx & 63;
          if (par_ok(v[k], pm))
            *reinterpret_cast<u32x4*>(smem + rr * 1024 + seg * 16) = v[k];
          else { np |= 1 << k; v[k] = ld128_sys(src + rr * 512 + seg * 8); }
        }
        pend = np;
      }
    }
    __syncthreads();
    if (tid == 0) st_flag(&FP[(192 + bg) * 4], (u32)(t + 1));
    {
      int row = tid >> 5, j = tid & 31;
      const u16* hr = reinterpret_cast<const u16*>(smem) + row * 512;
      float s1 = 0.f, s2 = 0.f;
#pragma unroll
      for (int kk = 0; kk < 16; ++kk) {
        float v = bf2f(hr[j + kk * 32]);
        s1 += v; s2 += v * v;
      }
#pragma unroll
      for (int d = 1; d < 32; d <<= 1) { s1 += __shfl_xor(s1, d, 32); s2 += __shfl_xor(s2, d, 32); }
      float mu = s1 * (1.f / 512.f);
      float rs = rsqrtf(s2 * (1.f / 512.f) - mu * mu + 1e-5f);
      char* zn = smem + 16384;
#pragma unroll
      for (int kk = 0; kk < 16; ++kk) {
        int kcol = j + kk * 32;
        float v = bf2f(hr[kcol]);
        float nv = (v - mu) * rs * lng[kcol] + lnb[kcol];
        *reinterpret_cast<short*>(zn + row * 1024 + ((kcol * 2) ^ ((row & 7) << 4))) = f2bf(nv);
      }
    }
    __syncthreads();
    const char* ap = smem + 16384 + (size_t)l15 * 1024;
    f32x4 acc[2][2] = {};
#pragma unroll 4
    for (int ks = 0; ks < 16; ++ks) {
      bf16x8 a = *reinterpret_cast<const bf16x8*>(ap + ((ks * 64 + lq * 16) ^ swzrow));
      bf16x8 b0 = *reinterpret_cast<const bf16x8*>(bp0 + ks * 512);
      bf16x8 b1 = *reinterpret_cast<const bf16x8*>(bp1 + ks * 512);
      acc[0][ks & 1] = __builtin_amdgcn_mfma_f32_16x16x32_bf16(a, b0, acc[0][ks & 1], 0, 0, 0);
      acc[1][ks & 1] = __builtin_amdgcn_mfma_f32_16x16x32_bf16(a, b1, acc[1][ks & 1], 0, 0, 0);
    }
#pragma unroll
    for (int nfi = 0; nfi < 2; ++nfi) {
      int vcol = (w * 2 + nfi) * 16 + l15;
      float pbv = nfi ? pb1 : pb0;
#pragma unroll
      for (int r = 0; r < 4; ++r) {
        float vv = acc[nfi][0][r] + acc[nfi][1][r] + pbv;
        out[(size_t)(m0 + lq * 4 + r) * 262144 + (size_t)t * 256 + vcol] = vv;
      }
    }
    __syncthreads();
  }
}

// Grid: 200 blocks. 0..127 = L1, 128..191 = L0, 192..199 = proj.
__global__ __launch_bounds__(512, 1) void persist_kernel(
    const short* __restrict__ W0h, const short* __restrict__ W1,
    const float* __restrict__ table, const float* __restrict__ bias1,
    const int* __restrict__ xT,
    u16* __restrict__ h0ring, u16* __restrict__ h1ring, u32* __restrict__ flags,
    const short* __restrict__ pWswz, const float* __restrict__ lng,
    const float* __restrict__ lnb, const float* __restrict__ pb, float* __restrict__ out)
{
  __shared__ __align__(16) char smem[49408];
  const int bid = blockIdx.x, tid = threadIdx.x;
  if (bid < 128) {
    lstm_role<1>(smem, bid >> 4, bid & 15, tid, W1, nullptr, bias1, xT,
                 h0ring, h1ring, flags);
  } else if (bid < 192) {
    int idx = bid - 128;
    lstm_role<0>(smem, idx >> 3, idx & 7, tid, W0h, table, nullptr, xT,
                 h0ring, h1ring, flags);
  } else {
    proj_role(smem, bid - 192, tid, h1ring, flags, pWswz, lng, lnb, pb, out);
  }
}

extern "C" void kernel_launch(void* const* d_in, const int* in_sizes, int n_in,
                              void* d_out, int out_size, void* d_ws, size_t ws_size,
                              hipStream_t stream) {
  const int*   x    = (const int*)d_in[0];
  const float* emb  = (const float*)d_in[1];
  const float* W    = (const float*)d_in[2];
  const float* bias = (const float*)d_in[3];
  const float* lng  = (const float*)d_in[4];
  const float* lnb  = (const float*)d_in[5];
  const float* pW   = (const float*)d_in[6];
  const float* pb   = (const float*)d_in[7];
  float* out = (float*)d_out;

  char* ws = (char*)d_ws;
  short* W0h   = (short*)(ws + 0);           // 2 MB
  short* W1sw  = (short*)(ws + 2097152);     // 4 MB
  short* pWsw  = (short*)(ws + 6291456);     // 256 KB
  float* table = (float*)(ws + 6815744);     // 2 MB
  int*   xT    = (int*)(ws + 8912896);       // 512 KB
  u32*   flags = (u32*)(ws + 9437184);       // 8 KB (prog only)
  u16*   h0ring= (u16*)(ws + 9961472);       // 2 MB: 16 x [128][512] bf16 (parity LSB)
  u16*   h1ring= (u16*)(ws + 12058624);      // 2 MB
  short* W0x   = (short*)(ws + 14155776);    // 2 MB temp (table build)

  swz_generic<<<dim3(512), dim3(256), 0, stream>>>(W, W0h, 1024, 512, 16, 131072);
  swz_generic<<<dim3(1024), dim3(256), 0, stream>>>(W + 2048 * 1024, W1sw, 1024, 0, 32, 262144);
  swz_generic<<<dim3(64), dim3(256), 0, stream>>>(pW, pWsw, 512, 0, 16, 16384);
  xpose_kernel<<<dim3(512), dim3(256), 0, stream>>>(x, xT);
  swz_generic<<<dim3(512), dim3(256), 0, stream>>>(W, W0x, 1024, 0, 16, 131072);
  table_kernel<<<dim3(4, 16), dim3(512), 0, stream>>>(emb, W0x, bias, table);
  hipMemsetAsync(ws + 9437184, 0, 8192, stream);          // prog flags
  hipMemsetAsync(ws + 9961472, 0x01, 4194304, stream);    // rings: LSB=1 rejects epochs 0..15

  persist_kernel<<<dim3(200), dim3(512), 0, stream>>>(
      W0h, W1sw, table, bias + 2048, xT, h0ring, h1ring, flags,
      pWsw, lng, lnb, pb, out);
}